// Round 4
// baseline (207.109 us; speedup 1.0000x reference)
//
#include <hip/hip_runtime.h>
#include <hip/hip_bf16.h>

// B=8, F=4, T=S=1024, C=32, C2=64, NH=2, HD=16
// Single regular-launch persistent kernel: 256 blocks x 1024 threads.
// Each block: 2 passes of (q-TCL tile + kv-TCL tile) -> manual grid barrier
// (device-global counters, self-resetting, explicit fences) -> 2 passes of
// (attention + epilogue).
#define T_LEN 1024

typedef __attribute__((ext_vector_type(8))) short short8;   // 8 bf16 = 4 VGPR
typedef __attribute__((ext_vector_type(4))) short short4v;
typedef __attribute__((ext_vector_type(4))) float float4v;
typedef __attribute__((ext_vector_type(2))) unsigned uint2v;
typedef __attribute__((ext_vector_type(4))) unsigned uint4v;

__device__ unsigned g_bar[2];   // zero-init at load; self-reset each launch

__device__ __forceinline__ float gelu_exact(float x) {
    return 0.5f * x * (1.0f + erff(x * 0.70710678118654752440f));
}
__device__ __forceinline__ unsigned short f2bf(float f) {   // RNE
    unsigned u = __float_as_uint(f);
    u += 0x7fffu + ((u >> 16) & 1u);
    return (unsigned short)(u >> 16);
}
__device__ __forceinline__ unsigned pk2bf(float a, float b) {  // (lo=a, hi=b)
    __hip_bfloat162 h = __float22bfloat162_rn(make_float2(a, b));
    unsigned u;
    __builtin_memcpy(&u, &h, 4);
    return u;
}
__device__ __forceinline__ float fexp2(float x) {   // raw v_exp_f32 (2^x)
    float r;
    asm("v_exp_f32 %0, %1" : "=v"(r) : "v"(x));
    return r;
}

// In-register P^T transpose for swapped-QK attention (16x16 tiles).
__device__ __forceinline__ short8 xpose_p(float4v t0, float4v t1) {
    unsigned u0 = pk2bf(t0.x, t0.y);
    unsigned u1 = pk2bf(t0.z, t0.w);
    unsigned u2 = pk2bf(t1.x, t1.y);
    unsigned u3 = pk2bf(t1.z, t1.w);
    uint2v r0 = __builtin_amdgcn_permlane32_swap(u0, u2, false, false);
    uint2v r1 = __builtin_amdgcn_permlane32_swap(u1, u3, false, false);
    uint2v r2 = __builtin_amdgcn_permlane16_swap(r0.x, r0.y, false, false);
    uint2v r3 = __builtin_amdgcn_permlane16_swap(r1.x, r1.y, false, false);
    uint4v p = { r2.x, r3.x, r2.y, r3.y };
    short8 f;
    __builtin_memcpy(&f, &p, 16);
    return f;
}

// LDS layout (65536 B total, 2 blocks/CU capacity => 256 blocks always resident)
// pre-barrier (per pass):
//   Abuf   [0,12288)      q rows (re-staged per pass; kv rows in step3)
//   WbT    [12288,24576)  q conv weights (pass0 only, persists)
//   Hb     [24576,33792)
//   WpB    [33792,38400)  q proj weights (pass0 only)
//   qs[2]  [38400,48640)  pitch 40 shorts, 5120 B per pass  (persistent)
//   WpBkv  [48640,53248)  kv proj weights (pass0 only)
//   WbTkv  [53248,65536)  kv conv weights (pass0 only)
// post-barrier:
//   swc@0 swf@4608 swm@9216 sln@13824 shn@13952 sgv@18560   (<=23168)
//   sy0@24576 [24576,32768)  lbuf@32768 [32768,33792)
//   sy1@48640 [48640,56832)  (dead WpBkv/WbTkv region)
//   qs[2] persists @38400
__global__ __launch_bounds__(1024, 8) void mega(
    const float* __restrict__ cd, const float* __restrict__ pkv,
    const float* __restrict__ wqc, const float* __restrict__ bqc,
    const float* __restrict__ wqp, const float* __restrict__ bqp,
    const float* __restrict__ wkc, const float* __restrict__ bkc,
    const float* __restrict__ wkp, const float* __restrict__ bkp,
    const float* __restrict__ wvc, const float* __restrict__ bvc,
    const float* __restrict__ wvp, const float* __restrict__ bvp,
    const float* __restrict__ wcp, const float* __restrict__ lnw,
    const float* __restrict__ wfc, const float* __restrict__ wmp,
    unsigned short* __restrict__ kbf, unsigned short* __restrict__ vtbf,
    float* __restrict__ out)
{
    __shared__ __align__(16) char smem[65536];
    unsigned short* Abuf  = (unsigned short*)(smem);
    unsigned short* WbT   = (unsigned short*)(smem + 12288);
    unsigned short* Hb    = (unsigned short*)(smem + 24576);
    unsigned short* WpB   = (unsigned short*)(smem + 33792);
    unsigned short* WpBkv = (unsigned short*)(smem + 48640);
    unsigned short* WbTkv = (unsigned short*)(smem + 53248);

    const int tid = threadIdx.x;
    const int bid = blockIdx.x;            // 0..255
    const int bf = bid >> 3;               // constant across both passes
    const int b  = bid >> 5;
    const int kvmode = bid >> 7;           // 0 = K, 1 = V
    const int kn = (bid >> 4) & 7;
    const float* wc_kv = kvmode ? wvc : wkc;
    const float* bc_kv = kvmode ? bvc : bkc;
    const float* wp_kv = kvmode ? wvp : wkp;
    const float* bp_kv = kvmode ? bvp : bkp;
    const float SC = 0.36067376022224085f;    // 0.25 * log2(e)

    const int w = tid >> 6;       // wave 0..15
    const int ln = tid & 63;
    const int sn = ln & 15;
    const int quad = ln >> 4;
    const float4v zero = { 0.f, 0.f, 0.f, 0.f };

    // ================= pre-barrier: 2 passes of q-TCL + kv-TCL =============
#pragma unroll 1
    for (int pass = 0; pass < 2; ++pass) {
        const int tile = (bid << 1) | pass;
        const int t0  = (tile & 15) * 64;
        const int kt0 = (tile & 31) * 32;
        unsigned short* qs = (unsigned short*)(smem + 38400 + pass * 5120);

        // ---- step 1: q input rows -> Abuf; pass0: q weights -> WbT/WpB
#pragma unroll
        for (int it = 0; it < 2; ++it) {
            int idx = tid + it * 1024;            // 0..2047
            if (idx < 1536) {
                int s = idx >> 3;                 // 0..191
                int sub = idx & 7;
                int t = s / 3, tap = s - t * 3;
                int tau = t0 + t - 2 + tap;
                float4 xv = make_float4(0.f, 0.f, 0.f, 0.f);
                if (tau >= 0) xv = *(const float4*)&cd[((size_t)bf * T_LEN + tau) * 32 + sub * 4];
                short4v pk = { (short)f2bf(xv.x), (short)f2bf(xv.y),
                               (short)f2bf(xv.z), (short)f2bf(xv.w) };
                *(short4v*)&Abuf[t * 96 + tap * 32 + sub * 4] = pk;
            }
        }
        if (pass == 0) {
#pragma unroll
            for (int it = 0; it < 2; ++it) {
                int i4 = tid + it * 1024;
                if (i4 < 1536) {
                    int idx = i4 * 4;
                    int o = idx / 96, r = idx - o * 96;
                    float4 w4 = *(const float4*)&wqc[idx];
                    float we[4] = { w4.x, w4.y, w4.z, w4.w };
#pragma unroll
                    for (int e = 0; e < 4; ++e) {
                        int re = r + e, c = re / 3, tap = re - c * 3;
                        WbT[o * 96 + tap * 32 + c] = f2bf(we[e]);
                    }
                }
            }
            if (tid < 512) {
                int idx = tid * 4;
                int c = idx >> 6, o = idx & 63;
                float4 w4 = *(const float4*)&wqp[idx];
                short4v pk = { (short)f2bf(w4.x), (short)f2bf(w4.y),
                               (short)f2bf(w4.z), (short)f2bf(w4.w) };
                *(short4v*)&WpB[c * 72 + o] = pk;
            }
        }
        __syncthreads();

        // ---- step 2: q conv GEMM (16 waves): tm = w&3, on = w>>2
        {
            const int tm = w & 3;
            const int on = w >> 2;
            const unsigned short* ar = &Abuf[(tm * 16 + sn) * 96 + quad * 8];
            short8 a0 = *(const short8*)(ar + 0);
            short8 a1 = *(const short8*)(ar + 32);
            short8 a2 = *(const short8*)(ar + 64);
            const unsigned short* br = &WbT[(on * 16 + sn) * 96 + quad * 8];
            float4v c0 = zero;
            c0 = __builtin_amdgcn_mfma_f32_16x16x32_bf16(a0, *(const short8*)(br + 0),  c0, 0, 0, 0);
            c0 = __builtin_amdgcn_mfma_f32_16x16x32_bf16(a1, *(const short8*)(br + 32), c0, 0, 0, 0);
            c0 = __builtin_amdgcn_mfma_f32_16x16x32_bf16(a2, *(const short8*)(br + 64), c0, 0, 0, 0);
            const float bc0 = bqc[on * 16 + sn];
            float g0[4] = { gelu_exact(c0.x + bc0), gelu_exact(c0.y + bc0),
                            gelu_exact(c0.z + bc0), gelu_exact(c0.w + bc0) };
#pragma unroll
            for (int i = 0; i < 4; ++i)
                Hb[(tm * 16 + quad * 4 + i) * 72 + on * 16 + sn] = f2bf(g0[i]);
        }
        __syncthreads();

        // ---- step 3: waves 0..7: q proj -> qs[pass] | waves 8..15: kv staging
        if (w < 8) {
            const int tm = w & 3, cn = w >> 2;
            const unsigned short* hr = &Hb[(tm * 16 + sn) * 72 + quad * 8];
            short8 pa0 = *(const short8*)(hr + 0);
            short8 pa1 = *(const short8*)(hr + 32);
            const unsigned short* wr_ = &WpB[(cn * 16 + sn) * 72 + quad * 8];
            short8 pb0 = *(const short8*)(wr_ + 0);
            short8 pb1 = *(const short8*)(wr_ + 32);
            float4v pacc = zero;
            pacc = __builtin_amdgcn_mfma_f32_16x16x32_bf16(pa0, pb0, pacc, 0, 0, 0);
            pacc = __builtin_amdgcn_mfma_f32_16x16x32_bf16(pa1, pb1, pacc, 0, 0, 0);
            const float bpv = bqp[cn * 16 + sn];
            float v[4] = { (pacc.x + bpv) * SC, (pacc.y + bpv) * SC,
                           (pacc.z + bpv) * SC, (pacc.w + bpv) * SC };
#pragma unroll
            for (int i = 0; i < 4; ++i)
                qs[(tm * 16 + quad * 4 + i) * 40 + cn * 16 + sn] = f2bf(v[i]);
        } else {
            const int t2 = tid - 512;             // 0..511
            // kv input rows -> Abuf (768 units; Abuf free after step 2)
#pragma unroll
            for (int it = 0; it < 2; ++it) {
                int idx = t2 + it * 512;
                if (idx < 768) {
                    int s = idx >> 3;             // 0..95
                    int sub = idx & 7;
                    int t = s / 3, tap = s - t * 3;
                    int tau = kt0 + t - 2 + tap;
                    float4 xv = make_float4(0.f, 0.f, 0.f, 0.f);
                    if (tau >= 0) xv = *(const float4*)&pkv[((size_t)kn * T_LEN + tau) * 32 + sub * 4];
                    short4v pk = { (short)f2bf(xv.x), (short)f2bf(xv.y),
                                   (short)f2bf(xv.z), (short)f2bf(xv.w) };
                    *(short4v*)&Abuf[t * 96 + tap * 32 + sub * 4] = pk;
                }
            }
            if (pass == 0) {
                // kv conv weights -> WbTkv (1536 float4 units)
#pragma unroll
                for (int it = 0; it < 3; ++it) {
                    int i4 = t2 + it * 512;       // 0..1535
                    int idx = i4 * 4;
                    int o = idx / 96, r = idx - o * 96;
                    float4 w4 = *(const float4*)&wc_kv[idx];
                    float we[4] = { w4.x, w4.y, w4.z, w4.w };
#pragma unroll
                    for (int e = 0; e < 4; ++e) {
                        int re = r + e, c = re / 3, tap = re - c * 3;
                        WbTkv[o * 96 + tap * 32 + c] = f2bf(we[e]);
                    }
                }
                // kv proj weights -> WpBkv (512 float4 units)
                {
                    int idx = t2 * 4;
                    int c = idx >> 6, o = idx & 63;
                    float4 w4 = *(const float4*)&wp_kv[idx];
                    short4v pk = { (short)f2bf(w4.x), (short)f2bf(w4.y),
                                   (short)f2bf(w4.z), (short)f2bf(w4.w) };
                    *(short4v*)&WpBkv[c * 72 + o] = pk;
                }
            }
        }
        __syncthreads();

        // ---- step 4: kv conv GEMM (waves 0..7): tm = w&1, on = w>>1
        if (w < 8) {
            const int tm = w & 1;
            const int on = w >> 1;                // 0..3
            const unsigned short* ar = &Abuf[(tm * 16 + sn) * 96 + quad * 8];
            short8 a0 = *(const short8*)(ar + 0);
            short8 a1 = *(const short8*)(ar + 32);
            short8 a2 = *(const short8*)(ar + 64);
            const unsigned short* br = &WbTkv[(on * 16 + sn) * 96 + quad * 8];
            float4v c0 = zero;
            c0 = __builtin_amdgcn_mfma_f32_16x16x32_bf16(a0, *(const short8*)(br + 0),  c0, 0, 0, 0);
            c0 = __builtin_amdgcn_mfma_f32_16x16x32_bf16(a1, *(const short8*)(br + 32), c0, 0, 0, 0);
            c0 = __builtin_amdgcn_mfma_f32_16x16x32_bf16(a2, *(const short8*)(br + 64), c0, 0, 0, 0);
            const float bc0 = bc_kv[on * 16 + sn];
            float g0[4] = { gelu_exact(c0.x + bc0), gelu_exact(c0.y + bc0),
                            gelu_exact(c0.z + bc0), gelu_exact(c0.w + bc0) };
#pragma unroll
            for (int i = 0; i < 4; ++i)
                Hb[(tm * 16 + quad * 4 + i) * 72 + on * 16 + sn] = f2bf(g0[i]);
        }
        __syncthreads();

        // ---- step 5: waves 0..3: kv proj -> global kbf/vtbf
        if (w < 4) {
            const int tm = w & 1, cn = w >> 1;    // cn 0..1
            const unsigned short* hr = &Hb[(tm * 16 + sn) * 72 + quad * 8];
            short8 pa0 = *(const short8*)(hr + 0);
            short8 pa1 = *(const short8*)(hr + 32);
            const unsigned short* wr_ = &WpBkv[(cn * 16 + sn) * 72 + quad * 8];
            short8 pb0 = *(const short8*)(wr_ + 0);
            short8 pb1 = *(const short8*)(wr_ + 32);
            float4v pacc = zero;
            pacc = __builtin_amdgcn_mfma_f32_16x16x32_bf16(pa0, pb0, pacc, 0, 0, 0);
            pacc = __builtin_amdgcn_mfma_f32_16x16x32_bf16(pa1, pb1, pacc, 0, 0, 0);
            const float bpv = bp_kv[cn * 16 + sn];
            float vv[4] = { pacc.x + bpv, pacc.y + bpv, pacc.z + bpv, pacc.w + bpv };
#pragma unroll
            for (int i = 0; i < 4; ++i) {
                int t = tm * 16 + quad * 4 + i;
                int c = cn * 16 + sn;
                if (kvmode == 0) {
                    kbf[((size_t)kn * T_LEN + kt0 + t) * 32 + c] = f2bf(vv[i]);
                } else {
                    vtbf[((size_t)(kn * 2 + cn) * 16 + sn) * T_LEN + kt0 + t] = f2bf(vv[i]);
                }
            }
        }
        __syncthreads();   // protects Abuf/Hb reuse next pass & orders stores
    }

    // ================= manual grid barrier (self-resetting) ================
    // __syncthreads above drained vmcnt -> this block's stores are in L2.
    if (tid == 0) {
        __threadfence();                              // release: L2 writeback
        __hip_atomic_fetch_add(&g_bar[0], 1u, __ATOMIC_SEQ_CST, __HIP_MEMORY_SCOPE_AGENT);
        unsigned sp = 0;
        while (__hip_atomic_load(&g_bar[0], __ATOMIC_SEQ_CST, __HIP_MEMORY_SCOPE_AGENT) < 256u) {
            if (++sp > (1u << 20)) break;             // bailout: no hard hang
            __builtin_amdgcn_s_sleep(2);
        }
        __threadfence();                              // acquire: L2 invalidate
        unsigned o2 = __hip_atomic_fetch_add(&g_bar[1], 1u, __ATOMIC_SEQ_CST, __HIP_MEMORY_SCOPE_AGENT);
        if (o2 == 255u) {                             // last through: reset for next replay
            __hip_atomic_store(&g_bar[0], 0u, __ATOMIC_SEQ_CST, __HIP_MEMORY_SCOPE_AGENT);
            __hip_atomic_store(&g_bar[1], 0u, __ATOMIC_SEQ_CST, __HIP_MEMORY_SCOPE_AGENT);
        }
    }
    __syncthreads();

    // ---- post-barrier: stage epilogue weights (Abuf/WbT regions now dead)
    {
        float* swc = (float*)(smem + 0);          // [32][36]
        float* swf = (float*)(smem + 4608);
        float* swm = (float*)(smem + 9216);
        float* sln = (float*)(smem + 13824);
        int r = tid >> 5, cc = tid & 31;          // tid 0..1023 covers all 1024
        swc[r * 36 + cc] = wcp[tid];
        swf[r * 36 + cc] = wfc[tid];
        swm[r * 36 + cc] = wmp[tid];
        if (tid < 32) sln[tid] = lnw[tid];
    }
    __syncthreads();

    // ================= post-barrier: 2 passes of attention + epilogue ======
    const short8 ones = { 16256, 16256, 16256, 16256,
                          16256, 16256, 16256, 16256 };   // bf16 1.0 x8
    const unsigned short* kb_base = kbf + (size_t)b * T_LEN * 32;
    const unsigned short* vb_base = vtbf + (size_t)b * 2 * 16 * T_LEN;

#pragma unroll 1
    for (int pass = 0; pass < 2; ++pass) {
        const int tile = (bid << 1) | pass;
        const int t0 = (tile & 15) * 64;
        unsigned short* qs = (unsigned short*)(smem + 38400 + pass * 5120);
        if (pass) __syncthreads();    // sy/lbuf reuse across passes

        // ---- attention: wave w -> head h=w&1, rt=(w>>1)&3, s-half sh=w>>3
        const int h = w & 1, rt = (w >> 1) & 3, sh = w >> 3;
        short8 aq = {0, 0, 0, 0, 0, 0, 0, 0};
        if (quad < 2)
            aq = *(const short8*)&qs[(rt * 16 + sn) * 40 + h * 16 + quad * 8];

        const unsigned short* kb = kb_base + h * 16 + quad * 8;
        const unsigned short* vb = vb_base + ((size_t)h * 16 + sn) * T_LEN + quad * 8;

        float4v yacc = zero;
        float4v lacc = zero;

        int s0 = sh << 9;
#pragma unroll 2
        for (int ii = 0; ii < 8; ++ii, s0 += 64) {
            short8 ka0 = {0,0,0,0,0,0,0,0}, ka1 = ka0, kc0 = ka0, kc1 = ka0;
            if (quad < 2) {
                ka0 = *(const short8*)(kb + (size_t)(s0 + sn) * 32);
                ka1 = *(const short8*)(kb + (size_t)(s0 + 16 + sn) * 32);
                kc0 = *(const short8*)(kb + (size_t)(s0 + 32 + sn) * 32);
                kc1 = *(const short8*)(kb + (size_t)(s0 + 48 + sn) * 32);
            }
            short8 bvA = *(const short8*)(vb + s0);
            short8 bvB = *(const short8*)(vb + s0 + 32);

            float4v cA0 = __builtin_amdgcn_mfma_f32_16x16x32_bf16(ka0, aq, zero, 0, 0, 0);
            float4v cA1 = __builtin_amdgcn_mfma_f32_16x16x32_bf16(ka1, aq, zero, 0, 0, 0);
            float4v cB0 = __builtin_amdgcn_mfma_f32_16x16x32_bf16(kc0, aq, zero, 0, 0, 0);
            float4v cB1 = __builtin_amdgcn_mfma_f32_16x16x32_bf16(kc1, aq, zero, 0, 0, 0);

            float4v eA0, eA1, eB0, eB1;
            eA0.x = fexp2(cA0.x); eA0.y = fexp2(cA0.y); eA0.z = fexp2(cA0.z); eA0.w = fexp2(cA0.w);
            eA1.x = fexp2(cA1.x); eA1.y = fexp2(cA1.y); eA1.z = fexp2(cA1.z); eA1.w = fexp2(cA1.w);
            eB0.x = fexp2(cB0.x); eB0.y = fexp2(cB0.y); eB0.z = fexp2(cB0.z); eB0.w = fexp2(cB0.w);
            eB1.x = fexp2(cB1.x); eB1.y = fexp2(cB1.y); eB1.z = fexp2(cB1.z); eB1.w = fexp2(cB1.w);

            short8 apA = xpose_p(eA0, eA1);
            short8 apB = xpose_p(eB0, eB1);

            yacc = __builtin_amdgcn_mfma_f32_16x16x32_bf16(bvA, apA, yacc, 0, 0, 0);
            yacc = __builtin_amdgcn_mfma_f32_16x16x32_bf16(bvB, apB, yacc, 0, 0, 0);
            lacc = __builtin_amdgcn_mfma_f32_16x16x32_bf16(ones, apA, lacc, 0, 0, 0);
            lacc = __builtin_amdgcn_mfma_f32_16x16x32_bf16(ones, apB, lacc, 0, 0, 0);
        }

        {
            float* syp = (float*)(smem + (sh ? 48640 : 24576));   // [64][32]
            *(float4v*)&syp[(rt * 16 + sn) * 32 + h * 16 + quad * 4] = yacc;
            float* lbuf = (float*)(smem + 32768);                 // [2sh][2h][64]
            if (quad == 0) lbuf[(sh * 2 + h) * 64 + rt * 16 + sn] = lacc.x;
        }
        __syncthreads();

        // ---- epilogue
        float* swc = (float*)(smem + 0);
        float* swf = (float*)(smem + 4608);
        float* swm = (float*)(smem + 9216);
        float* sln = (float*)(smem + 13824);
        float* shn = (float*)(smem + 13952);      // [32][36]
        float* sgv = (float*)(smem + 18560);      // [32][36]
        float* sy0 = (float*)(smem + 24576);
        float* sy1 = (float*)(smem + 48640);
        float* lbuf = (float*)(smem + 32768);

        const int rl = tid >> 5, c = tid & 31;    // rl 0..31
        const float lnwc = sln[c];
#pragma unroll 1
        for (int p = 0; p < 2; ++p) {
            int r = p * 32 + rl;
            size_t row = (size_t)bf * T_LEN + t0 + r;
            const float li0 = 1.0f / (lbuf[r] + lbuf[128 + r]);        // h=0
            const float li1 = 1.0f / (lbuf[64 + r] + lbuf[192 + r]);   // h=1
            float x1 = cd[row * 32 + c];
#pragma unroll
            for (int j4 = 0; j4 < 8; ++j4) {
                const float sc = (j4 < 4) ? li0 : li1;
                int yi = r * 32 + j4 * 4;
                float4 y0 = *(const float4*)&sy0[yi];
                float4 y1 = *(const float4*)&sy1[yi];
                float4 yv = make_float4((y0.x + y1.x) * sc, (y0.y + y1.y) * sc,
                                        (y0.z + y1.z) * sc, (y0.w + y1.w) * sc);
                const float* wv = &swc[c * 36 + j4 * 4];
                x1 += wv[0] * yv.x + wv[1] * yv.y + wv[2] * yv.z + wv[3] * yv.w;
            }
            float s1 = x1, s2 = x1 * x1;
#pragma unroll
            for (int off = 16; off; off >>= 1) {
                s1 += __shfl_xor(s1, off);
                s2 += __shfl_xor(s2, off);
            }
            float mu = s1 * (1.0f / 32.0f);
            float var = s2 * (1.0f / 32.0f) - mu * mu;
            float hn = (x1 - mu) * rsqrtf(var + 1e-5f) * lnwc;
            shn[rl * 36 + c] = hn;
            float ga = 0.f;
#pragma unroll
            for (int j4 = 0; j4 < 8; ++j4) {
                float4 hv = *(const float4*)&shn[rl * 36 + j4 * 4];
                const float* wv = &swf[c * 36 + j4 * 4];
                ga += wv[0] * hv.x + wv[1] * hv.y + wv[2] * hv.z + wv[3] * hv.w;
            }
            float gv = gelu_exact(ga);
            sgv[rl * 36 + c] = gv;
            float oa = x1;
#pragma unroll
            for (int j4 = 0; j4 < 8; ++j4) {
                float4 gvv = *(const float4*)&sgv[rl * 36 + j4 * 4];
                const float* wv = &swm[c * 36 + j4 * 4];
                oa += wv[0] * gvv.x + wv[1] * gvv.y + wv[2] * gvv.z + wv[3] * gvv.w;
            }
            out[row * 32 + c] = oa;
        }
    }
}

// ---------------------------------------------------------------------------
extern "C" void kernel_launch(void* const* d_in, const int* in_sizes, int n_in,
                              void* d_out, int out_size, void* d_ws, size_t ws_size,
                              hipStream_t stream) {
    const float* cd  = (const float*)d_in[0];
    const float* pkv = (const float*)d_in[1];
    const float* wqc = (const float*)d_in[2];
    const float* bqc = (const float*)d_in[3];
    const float* wqp = (const float*)d_in[4];
    const float* bqp = (const float*)d_in[5];
    const float* wkc = (const float*)d_in[6];
    const float* bkc = (const float*)d_in[7];
    const float* wkp = (const float*)d_in[8];
    const float* bkp = (const float*)d_in[9];
    const float* wvc = (const float*)d_in[10];
    const float* bvc = (const float*)d_in[11];
    const float* wvp = (const float*)d_in[12];
    const float* bvp = (const float*)d_in[13];
    const float* wcp = (const float*)d_in[14];
    const float* lnw = (const float*)d_in[15];
    const float* wfc = (const float*)d_in[16];
    const float* wmp = (const float*)d_in[17];

    // ws: kbf 0.5MB | vtbf 0.5MB
    unsigned short* kbf  = (unsigned short*)d_ws;
    unsigned short* vtbf = kbf + (size_t)8 * 1024 * 32;

    mega<<<256, 1024, 0, stream>>>(cd, pkv, wqc, bqc, wqp, bqp,
                                   wkc, bkc, wkp, bkp, wvc, bvc, wvp, bvp,
                                   wcp, lnw, wfc, wmp, kbf, vtbf, (float*)d_out);
}

// Round 6
// 133.905 us; speedup vs baseline: 1.5467x; 1.5467x over previous
//
#include <hip/hip_runtime.h>
#include <hip/hip_bf16.h>

// B=8, F=4, T=S=1024, C=32, C2=64, NH=2, HD=16
// Inputs fp32, output fp32. k/v staged bf16 in ws; q stays in LDS (fused).
// XCD co-location: batch n pinned to XCD n in BOTH kernels via bid%8.
#define T_LEN 1024

typedef __attribute__((ext_vector_type(8))) short short8;   // 8 bf16 = 4 VGPR
typedef __attribute__((ext_vector_type(4))) short short4v;
typedef __attribute__((ext_vector_type(4))) float float4v;
typedef __attribute__((ext_vector_type(2))) unsigned uint2v;
typedef __attribute__((ext_vector_type(4))) unsigned uint4v;

__device__ __forceinline__ float gelu_exact(float x) {
    return 0.5f * x * (1.0f + erff(x * 0.70710678118654752440f));
}
__device__ __forceinline__ unsigned short f2bf(float f) {   // RNE
    unsigned u = __float_as_uint(f);
    u += 0x7fffu + ((u >> 16) & 1u);
    return (unsigned short)(u >> 16);
}
__device__ __forceinline__ unsigned pk2bf(float a, float b) {  // (lo=a, hi=b)
    __hip_bfloat162 h = __float22bfloat162_rn(make_float2(a, b));
    unsigned u;
    __builtin_memcpy(&u, &h, 4);
    return u;
}

// In-register P^T transpose for swapped-QK attention (16x16 tiles).
// Input: two 16x16 C-tiles (col=q=lane&15, row=s=quad*4+reg), already exp'd.
// Output: B-operand fragment (col q=lane&15, k=s=quad*8+j) as 8 bf16.
__device__ __forceinline__ short8 xpose_p(float4v t0, float4v t1) {
    unsigned u0 = pk2bf(t0.x, t0.y);
    unsigned u1 = pk2bf(t0.z, t0.w);
    unsigned u2 = pk2bf(t1.x, t1.y);
    unsigned u3 = pk2bf(t1.z, t1.w);
    uint2v r0 = __builtin_amdgcn_permlane32_swap(u0, u2, false, false);
    uint2v r1 = __builtin_amdgcn_permlane32_swap(u1, u3, false, false);
    uint2v r2 = __builtin_amdgcn_permlane16_swap(r0.x, r0.y, false, false);
    uint2v r3 = __builtin_amdgcn_permlane16_swap(r1.x, r1.y, false, false);
    uint4v p = { r2.x, r3.x, r2.y, r3.y };
    short8 f;
    __builtin_memcpy(&f, &p, 16);
    return f;
}

// ---------------------------------------------------------------------------
// kv_tcl: k/v TCL, 512 blocks x 256 thr, 32-row tiles.
// XCD-aware: n = gb & 7 (batch n -> XCD n), tile = (gb>>3)&31.
// [0,256): k -> kbf [8][1024][32]; [256,512): v -> vtbf [8][2][16][1024].
// ---------------------------------------------------------------------------
__global__ __launch_bounds__(256) void kv_tcl(
    const float* __restrict__ pkv,
    const float* __restrict__ wkc, const float* __restrict__ bkc,
    const float* __restrict__ wkp, const float* __restrict__ bkp,
    const float* __restrict__ wvc, const float* __restrict__ bvc,
    const float* __restrict__ wvp, const float* __restrict__ bvp,
    unsigned short* __restrict__ kbf, unsigned short* __restrict__ vtbf)
{
    __shared__ __align__(16) unsigned short Abuf[32 * 96];
    __shared__ __align__(16) unsigned short WbT[64 * 96];
    __shared__ __align__(16) unsigned short Hb[32 * 72];
    __shared__ __align__(16) unsigned short WpB[32 * 72];

    const int tid = threadIdx.x;
    const int gb = blockIdx.x;

    const float *wc, *bc, *wp, *bp;
    unsigned short* outb;
    int mode;
    if (gb < 256) { wc = wkc; bc = bkc; wp = wkp; bp = bkp; outb = kbf;  mode = 0; }
    else          { wc = wvc; bc = bvc; wp = wvp; bp = bvp; outb = vtbf; mode = 1; }
    const int n  = gb & 7;                 // batch -> XCD (256 % 8 == 0, V too)
    const int t0 = ((gb >> 3) & 31) * 32;

#pragma unroll
    for (int it = 0; it < 3; ++it) {
        int s = (tid + it * 256) >> 3;
        int sub = tid & 7;
        int t = s / 3, tap = s - t * 3;
        int tau = t0 + t - 2 + tap;
        float4 xv = make_float4(0.f, 0.f, 0.f, 0.f);
        if (tau >= 0) xv = *(const float4*)&pkv[((size_t)n * T_LEN + tau) * 32 + sub * 4];
        short4v pk = { (short)f2bf(xv.x), (short)f2bf(xv.y),
                       (short)f2bf(xv.z), (short)f2bf(xv.w) };
        *(short4v*)&Abuf[t * 96 + tap * 32 + sub * 4] = pk;
    }
#pragma unroll
    for (int it = 0; it < 6; ++it) {
        int i4 = tid + it * 256;
        int idx = i4 * 4;
        int o = idx / 96, r = idx - o * 96;
        float4 w4 = *(const float4*)&wc[idx];
        float we[4] = { w4.x, w4.y, w4.z, w4.w };
#pragma unroll
        for (int e = 0; e < 4; ++e) {
            int re = r + e, c = re / 3, tap = re - c * 3;
            WbT[o * 96 + tap * 32 + c] = f2bf(we[e]);
        }
    }
#pragma unroll
    for (int it = 0; it < 2; ++it) {
        int i4 = tid + it * 256;
        int idx = i4 * 4;
        int c = idx >> 6, o = idx & 63;
        float4 w4 = *(const float4*)&wp[idx];
        short4v pk = { (short)f2bf(w4.x), (short)f2bf(w4.y),
                       (short)f2bf(w4.z), (short)f2bf(w4.w) };
        *(short4v*)&WpB[c * 72 + o] = pk;
    }

    const int w = tid >> 6;
    const int ln = tid & 63;
    const int sn = ln & 15;
    const int quad = ln >> 4;

    const float bcv = bc[w * 16 + sn];
    const int tmw = w & 1, cnw = w >> 1;
    const float bpv = bp[cnw * 16 + sn];

    __syncthreads();

    short8 b0 = *(const short8*)&WbT[(w * 16 + sn) * 96 + 0  + quad * 8];
    short8 b1 = *(const short8*)&WbT[(w * 16 + sn) * 96 + 32 + quad * 8];
    short8 b2 = *(const short8*)&WbT[(w * 16 + sn) * 96 + 64 + quad * 8];
    float4v zero = { 0.f, 0.f, 0.f, 0.f };
    float4v acc[2] = { zero, zero };
#pragma unroll
    for (int tm = 0; tm < 2; ++tm) {
        const unsigned short* ar = &Abuf[(tm * 16 + sn) * 96 + quad * 8];
        short8 a0 = *(const short8*)(ar + 0);
        short8 a1 = *(const short8*)(ar + 32);
        short8 a2 = *(const short8*)(ar + 64);
        acc[tm] = __builtin_amdgcn_mfma_f32_16x16x32_bf16(a0, b0, acc[tm], 0, 0, 0);
        acc[tm] = __builtin_amdgcn_mfma_f32_16x16x32_bf16(a1, b1, acc[tm], 0, 0, 0);
        acc[tm] = __builtin_amdgcn_mfma_f32_16x16x32_bf16(a2, b2, acc[tm], 0, 0, 0);
    }
#pragma unroll
    for (int tm = 0; tm < 2; ++tm) {
        float ge[4];
        ge[0] = gelu_exact(acc[tm].x + bcv);
        ge[1] = gelu_exact(acc[tm].y + bcv);
        ge[2] = gelu_exact(acc[tm].z + bcv);
        ge[3] = gelu_exact(acc[tm].w + bcv);
#pragma unroll
        for (int i = 0; i < 4; ++i)
            Hb[(tm * 16 + quad * 4 + i) * 72 + w * 16 + sn] = f2bf(ge[i]);
    }

    __syncthreads();

    const unsigned short* hr = &Hb[(tmw * 16 + sn) * 72 + quad * 8];
    short8 pa0 = *(const short8*)(hr + 0);
    short8 pa1 = *(const short8*)(hr + 32);
    short8 pb0 = *(const short8*)&WpB[(cnw * 16 + sn) * 72 + quad * 8];
    short8 pb1 = *(const short8*)&WpB[(cnw * 16 + sn) * 72 + 32 + quad * 8];
    float4v pacc = zero;
    pacc = __builtin_amdgcn_mfma_f32_16x16x32_bf16(pa0, pb0, pacc, 0, 0, 0);
    pacc = __builtin_amdgcn_mfma_f32_16x16x32_bf16(pa1, pb1, pacc, 0, 0, 0);

    float v[4] = { pacc.x + bpv, pacc.y + bpv, pacc.z + bpv, pacc.w + bpv };
#pragma unroll
    for (int i = 0; i < 4; ++i) {
        int t = tmw * 16 + quad * 4 + i;
        int c = cnw * 16 + sn;
        if (mode == 0) {
            outb[((size_t)n * T_LEN + t0 + t) * 32 + c] = f2bf(v[i]);
        } else {
            outb[((size_t)(n * 2 + cnw) * 16 + sn) * T_LEN + t0 + t] = f2bf(v[i]);
        }
    }
}

// ---------------------------------------------------------------------------
// fused_qae: per (bf, 64-row t-tile): q-TCL -> LDS, attention (8 waves =
// 4 row-tiles x 2 heads, swapped QK + in-register P^T transpose), epilogue.
// 512 blocks x 512 threads. XCD-aware: b = bid & 7 (same XCD as producers).
// LDS overlay (43520 B total):
//   phase A: Abuf[0,12288) WbT[12288,24576) Hb[24576,33792) WpB[33792,38400)
//   persistent: qs[38400,43520) (pitch 40 shorts; SC-prescaled q)
//   phase C weights staged early: swc@0 swf@4608 swm@9216 sln@13824
//   phase B out: sy@24576 [64][32]f32 (overlays dead Hb/WpB)
//   phase C scratch: shn@13952 sg@16256 (pitch 36 floats)
// ---------------------------------------------------------------------------
__global__ __launch_bounds__(512) void fused_qae(
    const float* __restrict__ cd,
    const float* __restrict__ wqc, const float* __restrict__ bqc,
    const float* __restrict__ wqp, const float* __restrict__ bqp,
    const unsigned short* __restrict__ kbf,
    const unsigned short* __restrict__ vtbf,
    const float* __restrict__ wcp, const float* __restrict__ lnw,
    const float* __restrict__ wfc, const float* __restrict__ wmp,
    float* __restrict__ out)
{
    __shared__ __align__(16) char smem[43520];
    unsigned short* Abuf = (unsigned short*)(smem);
    unsigned short* WbT  = (unsigned short*)(smem + 12288);
    unsigned short* Hb   = (unsigned short*)(smem + 24576);
    unsigned short* WpB  = (unsigned short*)(smem + 33792);
    unsigned short* qs   = (unsigned short*)(smem + 38400);

    const int tid = threadIdx.x;
    const int bid = blockIdx.x;
    const int b  = bid & 7;                // batch -> XCD (bid % 8)
    const int f_ = (bid >> 3) & 3;
    const int bf = b * 4 + f_;
    const int tt = bid >> 5;               // 0..15
    const int t0 = tt * 64;
    const float SC = 0.36067376022224085f;    // 0.25 * log2(e)

    // ---- phase A staging (512 threads)
#pragma unroll
    for (int it = 0; it < 3; ++it) {
        int idx = tid + it * 512;             // 0..1535
        int s = idx >> 3;                     // 0..191
        int sub = idx & 7;
        int t = s / 3, tap = s - t * 3;
        int tau = t0 + t - 2 + tap;
        float4 xv = make_float4(0.f, 0.f, 0.f, 0.f);
        if (tau >= 0) xv = *(const float4*)&cd[((size_t)bf * T_LEN + tau) * 32 + sub * 4];
        short4v pk = { (short)f2bf(xv.x), (short)f2bf(xv.y),
                       (short)f2bf(xv.z), (short)f2bf(xv.w) };
        *(short4v*)&Abuf[t * 96 + tap * 32 + sub * 4] = pk;
    }
#pragma unroll
    for (int it = 0; it < 3; ++it) {
        int i4 = tid + it * 512;              // 0..1535
        int idx = i4 * 4;
        int o = idx / 96, r = idx - o * 96;
        float4 w4 = *(const float4*)&wqc[idx];
        float we[4] = { w4.x, w4.y, w4.z, w4.w };
#pragma unroll
        for (int e = 0; e < 4; ++e) {
            int re = r + e, c = re / 3, tap = re - c * 3;
            WbT[o * 96 + tap * 32 + c] = f2bf(we[e]);
        }
    }
    {
        int idx = tid * 4;                    // 512 float4s
        int c = idx >> 6, o = idx & 63;
        float4 w4 = *(const float4*)&wqp[idx];
        short4v pk = { (short)f2bf(w4.x), (short)f2bf(w4.y),
                       (short)f2bf(w4.z), (short)f2bf(w4.w) };
        *(short4v*)&WpB[c * 72 + o] = pk;
    }

    const int w = tid >> 6;       // wave 0..7
    const int ln = tid & 63;
    const int sn = ln & 15;
    const int quad = ln >> 4;
    const float4v zero = { 0.f, 0.f, 0.f, 0.f };

    __syncthreads();

    // ---- phase A conv GEMM: wave w -> t-tile w&3, o-tiles {w>>2, w>>2+2}
    {
        const int tm = w & 3;
        const int on0 = w >> 2, on1 = on0 + 2;
        const unsigned short* ar = &Abuf[(tm * 16 + sn) * 96 + quad * 8];
        short8 a0 = *(const short8*)(ar + 0);
        short8 a1 = *(const short8*)(ar + 32);
        short8 a2 = *(const short8*)(ar + 64);
        const unsigned short* br0 = &WbT[(on0 * 16 + sn) * 96 + quad * 8];
        const unsigned short* br1 = &WbT[(on1 * 16 + sn) * 96 + quad * 8];
        float4v c0 = zero, c1 = zero;
        c0 = __builtin_amdgcn_mfma_f32_16x16x32_bf16(a0, *(const short8*)(br0 + 0),  c0, 0, 0, 0);
        c0 = __builtin_amdgcn_mfma_f32_16x16x32_bf16(a1, *(const short8*)(br0 + 32), c0, 0, 0, 0);
        c0 = __builtin_amdgcn_mfma_f32_16x16x32_bf16(a2, *(const short8*)(br0 + 64), c0, 0, 0, 0);
        c1 = __builtin_amdgcn_mfma_f32_16x16x32_bf16(a0, *(const short8*)(br1 + 0),  c1, 0, 0, 0);
        c1 = __builtin_amdgcn_mfma_f32_16x16x32_bf16(a1, *(const short8*)(br1 + 32), c1, 0, 0, 0);
        c1 = __builtin_amdgcn_mfma_f32_16x16x32_bf16(a2, *(const short8*)(br1 + 64), c1, 0, 0, 0);
        const float bc0 = bqc[on0 * 16 + sn], bc1 = bqc[on1 * 16 + sn];
        float g0[4] = { gelu_exact(c0.x + bc0), gelu_exact(c0.y + bc0),
                        gelu_exact(c0.z + bc0), gelu_exact(c0.w + bc0) };
        float g1[4] = { gelu_exact(c1.x + bc1), gelu_exact(c1.y + bc1),
                        gelu_exact(c1.z + bc1), gelu_exact(c1.w + bc1) };
#pragma unroll
        for (int i = 0; i < 4; ++i) {
            Hb[(tm * 16 + quad * 4 + i) * 72 + on0 * 16 + sn] = f2bf(g0[i]);
            Hb[(tm * 16 + quad * 4 + i) * 72 + on1 * 16 + sn] = f2bf(g1[i]);
        }
    }
    __syncthreads();

    // ---- phase A proj GEMM -> qs (pre-scaled by SC)
    {
        const int tm = w & 3, cn = w >> 2;
        const unsigned short* hr = &Hb[(tm * 16 + sn) * 72 + quad * 8];
        short8 pa0 = *(const short8*)(hr + 0);
        short8 pa1 = *(const short8*)(hr + 32);
        const unsigned short* wr_ = &WpB[(cn * 16 + sn) * 72 + quad * 8];
        short8 pb0 = *(const short8*)(wr_ + 0);
        short8 pb1 = *(const short8*)(wr_ + 32);
        float4v pacc = zero;
        pacc = __builtin_amdgcn_mfma_f32_16x16x32_bf16(pa0, pb0, pacc, 0, 0, 0);
        pacc = __builtin_amdgcn_mfma_f32_16x16x32_bf16(pa1, pb1, pacc, 0, 0, 0);
        const float bpv = bqp[cn * 16 + sn];
        float v[4] = { (pacc.x + bpv) * SC, (pacc.y + bpv) * SC,
                       (pacc.z + bpv) * SC, (pacc.w + bpv) * SC };
#pragma unroll
        for (int i = 0; i < 4; ++i)
            qs[(tm * 16 + quad * 4 + i) * 40 + cn * 16 + sn] = f2bf(v[i]);
    }

    // ---- phase C weight staging, hoisted (Abuf/WbT dead after conv GEMM)
    {
        float* swc = (float*)(smem + 0);          // [32][36]
        float* swf = (float*)(smem + 4608);
        float* swm = (float*)(smem + 9216);
        float* sln = (float*)(smem + 13824);
        for (int i = tid; i < 1024; i += 512) {
            int r = i >> 5, cc = i & 31;
            swc[r * 36 + cc] = wcp[i];
            swf[r * 36 + cc] = wfc[i];
            swm[r * 36 + cc] = wmp[i];
        }
        if (tid < 32) sln[tid] = lnw[tid];
    }
    __syncthreads();

    // ---- phase B attention (swapped operands): wave w -> head h = w&1,
    // row-tile rt = w>>1. QK^T computed as mfma(K, Q); P^T via permlane swaps.
    const int h = w & 1, rt = w >> 1;
    short8 aq = {0, 0, 0, 0, 0, 0, 0, 0};
    if (quad < 2)
        aq = *(const short8*)&qs[(rt * 16 + sn) * 40 + h * 16 + quad * 8];

    const unsigned short* kb = kbf + (size_t)b * T_LEN * 32 + h * 16 + quad * 8;
    const unsigned short* vb = vtbf + ((size_t)(b * 2 + h) * 16 + sn) * T_LEN + quad * 8;

    const short8 ones = { 16256, 16256, 16256, 16256,
                          16256, 16256, 16256, 16256 };   // bf16 1.0 x8
    float4v yacc = zero;
    float4v lacc = zero;

#pragma unroll 2
    for (int s0 = 0; s0 < 1024; s0 += 64) {
        short8 ka0 = {0,0,0,0,0,0,0,0}, ka1 = ka0, kc0 = ka0, kc1 = ka0;
        if (quad < 2) {
            ka0 = *(const short8*)(kb + (size_t)(s0 + sn) * 32);
            ka1 = *(const short8*)(kb + (size_t)(s0 + 16 + sn) * 32);
            kc0 = *(const short8*)(kb + (size_t)(s0 + 32 + sn) * 32);
            kc1 = *(const short8*)(kb + (size_t)(s0 + 48 + sn) * 32);
        }
        short8 bvA = *(const short8*)(vb + s0);
        short8 bvB = *(const short8*)(vb + s0 + 32);

        // swapped QK: C[col=q=sn][row=s=quad*4+reg]
        float4v cA0 = __builtin_amdgcn_mfma_f32_16x16x32_bf16(ka0, aq, zero, 0, 0, 0);
        float4v cA1 = __builtin_amdgcn_mfma_f32_16x16x32_bf16(ka1, aq, zero, 0, 0, 0);
        float4v cB0 = __builtin_amdgcn_mfma_f32_16x16x32_bf16(kc0, aq, zero, 0, 0, 0);
        float4v cB1 = __builtin_amdgcn_mfma_f32_16x16x32_bf16(kc1, aq, zero, 0, 0, 0);

        // q pre-scaled -> exp2 directly on MFMA output
        float4v eA0, eA1, eB0, eB1;
        eA0.x = exp2f(cA0.x); eA0.y = exp2f(cA0.y); eA0.z = exp2f(cA0.z); eA0.w = exp2f(cA0.w);
        eA1.x = exp2f(cA1.x); eA1.y = exp2f(cA1.y); eA1.z = exp2f(cA1.z); eA1.w = exp2f(cA1.w);
        eB0.x = exp2f(cB0.x); eB0.y = exp2f(cB0.y); eB0.z = exp2f(cB0.z); eB0.w = exp2f(cB0.w);
        eB1.x = exp2f(cB1.x); eB1.y = exp2f(cB1.y); eB1.z = exp2f(cB1.z); eB1.w = exp2f(cB1.w);

        short8 apA = xpose_p(eA0, eA1);   // s-chunk [s0, s0+32)
        short8 apB = xpose_p(eB0, eB1);   // s-chunk [s0+32, s0+64)

        // y^T = V^T * P^T : C[col=q=sn][row=d=quad*4+reg]
        yacc = __builtin_amdgcn_mfma_f32_16x16x32_bf16(bvA, apA, yacc, 0, 0, 0);
        yacc = __builtin_amdgcn_mfma_f32_16x16x32_bf16(bvB, apB, yacc, 0, 0, 0);
        // l[q] = ones * P^T : every reg/quad = sum_s P[q][s]
        lacc = __builtin_amdgcn_mfma_f32_16x16x32_bf16(ones, apA, lacc, 0, 0, 0);
        lacc = __builtin_amdgcn_mfma_f32_16x16x32_bf16(ones, apB, lacc, 0, 0, 0);
    }

    // normalized y -> sy (overlays dead Hb/WpB)
    float* sy = (float*)(smem + 24576);       // [64][32]
    {
        const float linv = 1.0f / lacc.x;     // l[q=sn], same in all regs
        float4v yn = { yacc.x * linv, yacc.y * linv,
                       yacc.z * linv, yacc.w * linv };
        *(float4v*)&sy[(rt * 16 + sn) * 32 + h * 16 + quad * 4] = yn;
    }
    __syncthreads();

    // ---- phase C epilogue (weights already staged at [0,13952))
    float* swc = (float*)(smem + 0);          // [32][36]
    float* swf = (float*)(smem + 4608);
    float* swm = (float*)(smem + 9216);
    float* sln = (float*)(smem + 13824);
    float* shn = (float*)(smem + 13952);      // [16][36]
    float* sgv = (float*)(smem + 16256);

    const int rl = tid >> 5, c = tid & 31;
    const float lnwc = sln[c];
#pragma unroll 1
    for (int p = 0; p < 4; ++p) {
        int r = p * 16 + rl;
        size_t row = (size_t)bf * T_LEN + t0 + r;
        float x1 = cd[row * 32 + c];
#pragma unroll
        for (int j4 = 0; j4 < 8; ++j4) {
            float4 yv = *(const float4*)&sy[r * 32 + j4 * 4];
            const float* wv = &swc[c * 36 + j4 * 4];
            x1 += wv[0] * yv.x + wv[1] * yv.y + wv[2] * yv.z + wv[3] * yv.w;
        }
        float s1 = x1, s2 = x1 * x1;
#pragma unroll
        for (int off = 16; off; off >>= 1) {
            s1 += __shfl_xor(s1, off);
            s2 += __shfl_xor(s2, off);
        }
        float mu = s1 * (1.0f / 32.0f);
        float var = s2 * (1.0f / 32.0f) - mu * mu;
        float hn = (x1 - mu) * rsqrtf(var + 1e-5f) * lnwc;
        shn[rl * 36 + c] = hn;
        float ga = 0.f;
#pragma unroll
        for (int j4 = 0; j4 < 8; ++j4) {
            float4 hv = *(const float4*)&shn[rl * 36 + j4 * 4];
            const float* wv = &swf[c * 36 + j4 * 4];
            ga += wv[0] * hv.x + wv[1] * hv.y + wv[2] * hv.z + wv[3] * hv.w;
        }
        float gv = gelu_exact(ga);
        sgv[rl * 36 + c] = gv;
        float oa = x1;
#pragma unroll
        for (int j4 = 0; j4 < 8; ++j4) {
            float4 gvv = *(const float4*)&sgv[rl * 36 + j4 * 4];
            const float* wv = &swm[c * 36 + j4 * 4];
            oa += wv[0] * gvv.x + wv[1] * gvv.y + wv[2] * gvv.z + wv[3] * gvv.w;
        }
        out[row * 32 + c] = oa;
    }
}

// ---------------------------------------------------------------------------
extern "C" void kernel_launch(void* const* d_in, const int* in_sizes, int n_in,
                              void* d_out, int out_size, void* d_ws, size_t ws_size,
                              hipStream_t stream) {
    const float* cd  = (const float*)d_in[0];
    const float* pkv = (const float*)d_in[1];
    const float* wqc = (const float*)d_in[2];
    const float* bqc = (const float*)d_in[3];
    const float* wqp = (const float*)d_in[4];
    const float* bqp = (const float*)d_in[5];
    const float* wkc = (const float*)d_in[6];
    const float* bkc = (const float*)d_in[7];
    const float* wkp = (const float*)d_in[8];
    const float* bkp = (const float*)d_in[9];
    const float* wvc = (const float*)d_in[10];
    const float* bvc = (const float*)d_in[11];
    const float* wvp = (const float*)d_in[12];
    const float* bvp = (const float*)d_in[13];
    const float* wcp = (const float*)d_in[14];
    const float* lnw = (const float*)d_in[15];
    const float* wfc = (const float*)d_in[16];
    const float* wmp = (const float*)d_in[17];

    // ws: kbf 0.5MB | vtbf 0.5MB
    unsigned short* kbf  = (unsigned short*)d_ws;
    unsigned short* vtbf = kbf + (size_t)8 * 1024 * 32;

    kv_tcl<<<512, 256, 0, stream>>>(pkv, wkc, bkc, wkp, bkp,
                                    wvc, bvc, wvp, bvp, kbf, vtbf);
    fused_qae<<<512, 512, 0, stream>>>(cd, wqc, bqc, wqp, bqp, kbf, vtbf,
                                       wcp, lnw, wfc, wmp, (float*)d_out);
}